// Round 1
// baseline (2196.974 us; speedup 1.0000x reference)
//
#include <hip/hip_runtime.h>
#include <math.h>

static constexpr int BATCH = 4096;
static constexpr int NVIS  = 1024;
static constexpr int NHID  = 4096;
static constexpr int NCOND = 512;

#define TS  64   // output tile (M and N)
#define KS  16   // k-step
#define LDP 66   // padded row length (doubles); 66*8=528B keeps 16B alignment

// 16-step f64 MMA on transposed LDS tiles As[kk][m], Bs[kk][n]
__device__ __forceinline__ void mma16(const double (&As)[KS][LDP],
                                      const double (&Bs)[KS][LDP],
                                      double (&acc)[4][4], int tx, int ty)
{
#pragma unroll
    for (int kk = 0; kk < KS; ++kk) {
        const double2* ap = reinterpret_cast<const double2*>(&As[kk][ty * 4]);
        const double2* bp = reinterpret_cast<const double2*>(&Bs[kk][tx * 4]);
        double2 a0 = ap[0], a1 = ap[1];
        double2 b0 = bp[0], b1 = bp[1];
        double a[4] = {a0.x, a0.y, a1.x, a1.y};
        double b[4] = {b0.x, b0.y, b1.x, b1.y};
#pragma unroll
        for (int ii = 0; ii < 4; ++ii)
#pragma unroll
            for (int jj = 0; jj < 4; ++jj)
                acc[ii][jj] = fma(a[ii], b[jj], acc[ii][jj]);
    }
}

// ---------------------------------------------------------------------------
// k1: z = v@W + u@Bm + c ; h = (noise < sigmoid(z)) ? 1 : 0   (u8)
// grid: (NHID/TS, BATCH/TS), 256 threads
// ---------------------------------------------------------------------------
__global__ __launch_bounds__(256) void k1_hsample(
    const float* __restrict__ vd,    // [BATCH, NVIS]
    const float* __restrict__ cd,    // [BATCH, NCOND]
    const float* __restrict__ noise, // [BATCH, NHID]
    const float* __restrict__ W,     // [NVIS, NHID]
    const float* __restrict__ Bm,    // [NCOND, NHID]
    const float* __restrict__ cb,    // [NHID]
    unsigned char* __restrict__ h)   // [BATCH, NHID]
{
    __shared__ double As[KS][LDP];
    __shared__ double Bs[KS][LDP];
    const int b0 = blockIdx.y * TS;
    const int j0 = blockIdx.x * TS;
    const int t  = threadIdx.x;
    const int tx = t & 15, ty = t >> 4;
    double acc[4][4] = {};

    // phase 1: K = NVIS, A = vd, B = W  (W rows contiguous along j)
    for (int k0 = 0; k0 < NVIS; k0 += KS) {
        __syncthreads();
#pragma unroll
        for (int e = 0; e < 4; ++e) {
            int idx = t + e * 256;
            int r  = idx >> 4, ka = idx & 15;          // A: 16 consec floats / 16 lanes
            As[ka][r] = (double)vd[(size_t)(b0 + r) * NVIS + k0 + ka];
            int kb = idx >> 6, cj = idx & 63;          // B: 64 consec floats / 64 lanes
            Bs[kb][cj] = (double)W[(size_t)(k0 + kb) * NHID + j0 + cj];
        }
        __syncthreads();
        mma16(As, Bs, acc, tx, ty);
    }
    // phase 2: K = NCOND, A = cd, B = Bm
    for (int k0 = 0; k0 < NCOND; k0 += KS) {
        __syncthreads();
#pragma unroll
        for (int e = 0; e < 4; ++e) {
            int idx = t + e * 256;
            int r  = idx >> 4, ka = idx & 15;
            As[ka][r] = (double)cd[(size_t)(b0 + r) * NCOND + k0 + ka];
            int kb = idx >> 6, cj = idx & 63;
            Bs[kb][cj] = (double)Bm[(size_t)(k0 + kb) * NHID + j0 + cj];
        }
        __syncthreads();
        mma16(As, Bs, acc, tx, ty);
    }
    // epilogue: +c, sigmoid (f64), bernoulli via (noise < mean)
#pragma unroll
    for (int ii = 0; ii < 4; ++ii) {
        int b = b0 + ty * 4 + ii;
        const float4 nz = *reinterpret_cast<const float4*>(
            &noise[(size_t)b * NHID + j0 + tx * 4]);
        float nzv[4] = {nz.x, nz.y, nz.z, nz.w};
        unsigned char hh[4];
#pragma unroll
        for (int jj = 0; jj < 4; ++jj) {
            int j = j0 + tx * 4 + jj;
            double z = acc[ii][jj] + (double)cb[j];
            double m = 1.0 / (1.0 + exp(-z));
            hh[jj] = ((double)nzv[jj] < m) ? (unsigned char)1 : (unsigned char)0;
        }
        *reinterpret_cast<uchar4*>(&h[(size_t)b * NHID + j0 + tx * 4]) =
            make_uchar4(hh[0], hh[1], hh[2], hh[3]);
    }
}

// ---------------------------------------------------------------------------
// k2: pre = h@W^T + u@A + b   (f64 out to ws)
// grid: (NVIS/TS, BATCH/TS), 256 threads
// ---------------------------------------------------------------------------
__global__ __launch_bounds__(256) void k2_pre(
    const unsigned char* __restrict__ h, // [BATCH, NHID]
    const float* __restrict__ cd,        // [BATCH, NCOND]
    const float* __restrict__ W,         // [NVIS, NHID]
    const float* __restrict__ A,         // [NCOND, NVIS]
    const float* __restrict__ bvec,      // [NVIS]
    double* __restrict__ pre)            // [BATCH, NVIS]
{
    __shared__ double Hs[KS][LDP];
    __shared__ double Ws[KS][LDP];
    const int b0 = blockIdx.y * TS;
    const int i0 = blockIdx.x * TS;
    const int t  = threadIdx.x;
    const int tx = t & 15, ty = t >> 4;
    double acc[4][4] = {};

    // phase 1: K = NHID, A-op = h (u8 -> f64), B-op = W^T (Ws[kk][i] = W[i, kk])
    for (int k0 = 0; k0 < NHID; k0 += KS) {
        __syncthreads();
#pragma unroll
        for (int e = 0; e < 4; ++e) {
            int idx = t + e * 256;
            int r  = idx >> 4, ka = idx & 15;
            Hs[ka][r] = (double)h[(size_t)(b0 + r) * NHID + k0 + ka];
            int i = idx >> 4, kb = idx & 15;           // 16 consec floats / 16 lanes
            Ws[kb][i] = (double)W[(size_t)(i0 + i) * NHID + k0 + kb];
        }
        __syncthreads();
        mma16(Hs, Ws, acc, tx, ty);
    }
    // phase 2: K = NCOND, A-op = cd, B-op = A  (A rows contiguous along i)
    for (int k0 = 0; k0 < NCOND; k0 += KS) {
        __syncthreads();
#pragma unroll
        for (int e = 0; e < 4; ++e) {
            int idx = t + e * 256;
            int r  = idx >> 4, ka = idx & 15;
            Hs[ka][r] = (double)cd[(size_t)(b0 + r) * NCOND + k0 + ka];
            int kb = idx >> 6, ci = idx & 63;
            Ws[kb][ci] = (double)A[(size_t)(k0 + kb) * NVIS + i0 + ci];
        }
        __syncthreads();
        mma16(Hs, Ws, acc, tx, ty);
    }
    // epilogue: + b
#pragma unroll
    for (int ii = 0; ii < 4; ++ii) {
        int b = b0 + ty * 4 + ii;
#pragma unroll
        for (int jj = 0; jj < 4; ++jj) {
            int i = i0 + tx * 4 + jj;
            pre[(size_t)b * NVIS + i] = acc[ii][jj] + (double)bvec[i];
        }
    }
}

// ---------------------------------------------------------------------------
// k3: per-row argmax (first-index tie-break) + one-hot write (full row)
// grid: BATCH blocks x 256 threads
// ---------------------------------------------------------------------------
__global__ __launch_bounds__(256) void k3_argmax(
    const double* __restrict__ pre, float* __restrict__ out)
{
    const int b = blockIdx.x;
    const int t = threadIdx.x;
    const double* row = pre + (size_t)b * NVIS;

    double best = row[t * 4];
    int bi = t * 4;
#pragma unroll
    for (int e = 1; e < 4; ++e) {
        double v = row[t * 4 + e];
        if (v > best) { best = v; bi = t * 4 + e; }  // strict > keeps first index
    }
    __shared__ double sv[256];
    __shared__ int    si[256];
    sv[t] = best; si[t] = bi;
    __syncthreads();
    for (int s = 128; s > 0; s >>= 1) {
        if (t < s) {
            double v2 = sv[t + s]; int i2 = si[t + s];
            if (v2 > sv[t] || (v2 == sv[t] && i2 < si[t])) { sv[t] = v2; si[t] = i2; }
        }
        __syncthreads();
    }
    const int amax = si[0];
    float* orow = out + (size_t)b * NVIS;
#pragma unroll
    for (int e = 0; e < 4; ++e) {
        int i = t + e * 256;
        orow[i] = (i == amax) ? 1.0f : 0.0f;
    }
}

extern "C" void kernel_launch(void* const* d_in, const int* in_sizes, int n_in,
                              void* d_out, int out_size, void* d_ws, size_t ws_size,
                              hipStream_t stream)
{
    const float* vd = (const float*)d_in[0];  // visible_data [4096,1024]
    const float* cd = (const float*)d_in[1];  // cond_data    [4096,512]
    const float* nz = (const float*)d_in[2];  // noise        [4096,4096]
    const float* W  = (const float*)d_in[3];  // W            [1024,4096]
    const float* bv = (const float*)d_in[4];  // b            [1024]
    const float* cv = (const float*)d_in[5];  // c            [4096]
    const float* A  = (const float*)d_in[6];  // A            [512,1024]
    const float* Bm = (const float*)d_in[7];  // B            [512,4096]
    float* out = (float*)d_out;

    unsigned char* h = (unsigned char*)d_ws;                       // 16 MB
    double* pre = (double*)((char*)d_ws + (size_t)BATCH * NHID);   // 32 MB

    dim3 blk(256);
    k1_hsample<<<dim3(NHID / TS, BATCH / TS), blk, 0, stream>>>(vd, cd, nz, W, Bm, cv, h);
    k2_pre<<<dim3(NVIS / TS, BATCH / TS), blk, 0, stream>>>(h, cd, W, A, bv, pre);
    k3_argmax<<<dim3(BATCH), blk, 0, stream>>>(pre, out);
}

// Round 2
// 780.298 us; speedup vs baseline: 2.8156x; 2.8156x over previous
//
#include <hip/hip_runtime.h>
#include <math.h>

static constexpr int BATCH = 4096;
static constexpr int NVIS  = 1024;
static constexpr int NHID  = 4096;
static constexpr int NCOND = 512;

typedef __attribute__((ext_vector_type(8))) short bf16x8;
typedef __attribute__((ext_vector_type(4))) float f32x4;

static constexpr unsigned HCAP = 131072;
static constexpr unsigned RCAP = 256;

// ---------------- ws layout (bytes) ----------------
static constexpr size_t OFF_WT0   = 0;                      // [4096][1024] bf16
static constexpr size_t OFF_WT1   = OFF_WT0 + 8388608;
static constexpr size_t OFF_BMT0  = OFF_WT1 + 8388608;      // [4096][512] bf16
static constexpr size_t OFF_BMT1  = OFF_BMT0 + 4194304;
static constexpr size_t OFF_AT0   = OFF_BMT1 + 4194304;     // [1024][512] bf16
static constexpr size_t OFF_AT1   = OFF_AT0 + 1048576;
static constexpr size_t OFF_H     = OFF_AT1 + 1048576;      // [4096][4096] u8
static constexpr size_t OFF_BB    = OFF_H + 16777216;       // blockbest [4096][8] float4
static constexpr size_t OFF_HFLAG = OFF_BB + 524288;        // u32[HCAP]
static constexpr size_t OFF_RFLAG = OFF_HFLAG + 524288;     // u32[4096]
static constexpr size_t OFF_RBEST = OFF_RFLAG + 16384;      // u32[4096]
static constexpr size_t OFF_CNT   = OFF_RBEST + 16384;      // u32[64]
static constexpr size_t OFF_PREB  = OFF_CNT + 256;          // [256][1024] f64
static constexpr size_t WS_SMALL  = OFF_PREB + 2097152;     // 45.03 MiB
// big-mode extras
static constexpr size_t OFF_V0 = WS_SMALL;                  // [4096][1024] bf16
static constexpr size_t OFF_V1 = OFF_V0 + 8388608;
static constexpr size_t OFF_U0 = OFF_V1 + 8388608;          // [4096][512] bf16
static constexpr size_t OFF_U1 = OFF_U0 + 4194304;
static constexpr size_t OFF_W0 = OFF_U1 + 4194304;          // [1024][4096] bf16
static constexpr size_t OFF_W1 = OFF_W0 + 8388608;
static constexpr size_t WS_BIG = OFF_W1 + 8388608;          // 85.03 MiB

// ---------------- helpers ----------------
__device__ __forceinline__ void split1(float x, unsigned short& hi, unsigned short& lo) {
    unsigned u = __float_as_uint(x);
    unsigned r = u + 0x7FFFu + ((u >> 16) & 1u);      // RN-even f32->bf16
    hi = (unsigned short)(r >> 16);
    float rem = x - __uint_as_float(r & 0xFFFF0000u); // exact (Sterbenz)
    unsigned u2 = __float_as_uint(rem);
    unsigned r2 = u2 + 0x7FFFu + ((u2 >> 16) & 1u);
    lo = (unsigned short)(r2 >> 16);
}

// top2 merge with first-index tiebreak; invariant s<=b on both inputs
__device__ __forceinline__ void merge3(float& b, unsigned& ix, float& s,
                                       float b2, unsigned i2, float s2) {
    if (b2 > b || (b2 == b && i2 < ix)) { s = fmaxf(b, s2); b = b2; ix = i2; }
    else                                { s = fmaxf(s, b2); }
}

// ---------------- small prep kernels ----------------
__global__ void kz_zero(unsigned* c) { if (threadIdx.x < 64) c[threadIdx.x] = 0; }

// src [R][C] f32 -> d0/d1 [C][R] bf16 hi/lo planes
__global__ __launch_bounds__(256) void transpose_split(
    const float* __restrict__ src, int R, int C,
    unsigned short* __restrict__ d0, unsigned short* __restrict__ d1) {
    __shared__ float tile[32][33];
    const int c0 = blockIdx.x * 32, r0 = blockIdx.y * 32;
    const int tx = threadIdx.x & 31, ty = threadIdx.x >> 5;
#pragma unroll
    for (int e = 0; e < 4; ++e)
        tile[ty + e * 8][tx] = src[(size_t)(r0 + ty + e * 8) * C + c0 + tx];
    __syncthreads();
#pragma unroll
    for (int e = 0; e < 4; ++e) {
        int c = c0 + ty + e * 8;
        unsigned short hi, lo;
        split1(tile[tx][ty + e * 8], hi, lo);
        d0[(size_t)c * R + r0 + tx] = hi;
        d1[(size_t)c * R + r0 + tx] = lo;
    }
}

// elementwise split: src f32[n4*4] -> p0/p1 bf16 planes (same layout)
__global__ __launch_bounds__(256) void split_planes(
    const float* __restrict__ src, int n4,
    unsigned short* __restrict__ p0, unsigned short* __restrict__ p1) {
    for (int i = blockIdx.x * 256 + threadIdx.x; i < n4; i += gridDim.x * 256) {
        float4 v = ((const float4*)src)[i];
        unsigned short h0,h1,h2,h3,l0,l1,l2,l3;
        split1(v.x,h0,l0); split1(v.y,h1,l1); split1(v.z,h2,l2); split1(v.w,h3,l3);
        ((ushort4*)p0)[i] = make_ushort4(h0,h1,h2,h3);
        ((ushort4*)p1)[i] = make_ushort4(l0,l1,l2,l3);
    }
}

// ---------------- staging helpers (tile = [128 rows][32 k] bf16 in LDS) ----------------
__device__ __forceinline__ void stage_copy(const unsigned short* __restrict__ p,
                                           int r0, int k0, int stride,
                                           unsigned short (*lds)[32], int t) {
#pragma unroll
    for (int e = 0; e < 2; ++e) {
        int idx = t + e * 256, row = idx >> 2, s = idx & 3;
        *(bf16x8*)&lds[row][s * 8] =
            *(const bf16x8*)(p + (size_t)(r0 + row) * stride + k0 + s * 8);
    }
}
__device__ __forceinline__ void stage_split(const float* __restrict__ p,
                                            int r0, int k0, int stride,
                                            unsigned short (*l0)[32], unsigned short (*l1)[32], int t) {
#pragma unroll
    for (int e = 0; e < 4; ++e) {
        int idx = t + e * 256, row = idx >> 3, q = idx & 7;
        const float4 v = *(const float4*)(p + (size_t)(r0 + row) * stride + k0 + q * 4);
        unsigned short h0,h1,h2,h3, s0,s1,s2,s3;
        split1(v.x,h0,s0); split1(v.y,h1,s1); split1(v.z,h2,s2); split1(v.w,h3,s3);
        *(ushort4*)&l0[row][q * 4] = make_ushort4(h0,h1,h2,h3);
        *(ushort4*)&l1[row][q * 4] = make_ushort4(s0,s1,s2,s3);
    }
}
__device__ __forceinline__ void stage_hbits(const unsigned char* __restrict__ h,
                                            int r0, int k0,
                                            unsigned short (*lds)[32], int t) {
#pragma unroll
    for (int e = 0; e < 4; ++e) {
        int idx = t + e * 256, row = idx >> 3, q = idx & 7;
        uchar4 u = *(const uchar4*)(h + (size_t)(r0 + row) * NHID + k0 + q * 4);
        *(ushort4*)&lds[row][q * 4] = make_ushort4(u.x ? 0x3F80 : 0, u.y ? 0x3F80 : 0,
                                                   u.z ? 0x3F80 : 0, u.w ? 0x3F80 : 0);
    }
}

// ---------------- k1: z = v@W + u@B + c ; h = noise < sigmoid(z); flag boundary ----------------
template <bool PRESPLIT>
__global__ __launch_bounds__(256) void k1_gemm(
    const float* __restrict__ vd, const float* __restrict__ cd, const float* __restrict__ noise,
    const unsigned short* __restrict__ v0p, const unsigned short* __restrict__ v1p,
    const unsigned short* __restrict__ u0p, const unsigned short* __restrict__ u1p,
    const unsigned short* __restrict__ WT0, const unsigned short* __restrict__ WT1,
    const unsigned short* __restrict__ BmT0, const unsigned short* __restrict__ BmT1,
    const float* __restrict__ cvec, unsigned char* __restrict__ hout,
    unsigned* __restrict__ hcnt, unsigned* __restrict__ hflag) {
    __shared__ __align__(16) unsigned short As0[128][32], As1[128][32], Bs0[128][32], Bs1[128][32];
    const int t = threadIdx.x, lane = t & 63, wid = t >> 6;
    const int g = lane >> 4, cc = lane & 15;
    const int wrow = wid >> 1, wcol = wid & 1;
    const int b0 = blockIdx.y * 128, j0 = blockIdx.x * 128;
    f32x4 acc[4][4] = {};

    for (int ph = 0; ph < 2; ++ph) {
        const int K = ph ? NCOND : NVIS;
        for (int k0 = 0; k0 < K; k0 += 32) {
            __syncthreads();
            if (ph == 0) {
                if (PRESPLIT) { stage_copy(v0p, b0, k0, NVIS, As0, t); stage_copy(v1p, b0, k0, NVIS, As1, t); }
                else          { stage_split(vd, b0, k0, NVIS, As0, As1, t); }
                stage_copy(WT0, j0, k0, NVIS, Bs0, t);
                stage_copy(WT1, j0, k0, NVIS, Bs1, t);
            } else {
                if (PRESPLIT) { stage_copy(u0p, b0, k0, NCOND, As0, t); stage_copy(u1p, b0, k0, NCOND, As1, t); }
                else          { stage_split(cd, b0, k0, NCOND, As0, As1, t); }
                stage_copy(BmT0, j0, k0, NCOND, Bs0, t);
                stage_copy(BmT1, j0, k0, NCOND, Bs1, t);
            }
            __syncthreads();
            bf16x8 a0[4], a1[4];
#pragma unroll
            for (int mi = 0; mi < 4; ++mi) {
                int r = wrow * 64 + mi * 16 + cc;
                a0[mi] = *(const bf16x8*)&As0[r][g * 8];
                a1[mi] = *(const bf16x8*)&As1[r][g * 8];
            }
#pragma unroll
            for (int ni = 0; ni < 4; ++ni) {
                int n = wcol * 64 + ni * 16 + cc;
                bf16x8 bb0 = *(const bf16x8*)&Bs0[n][g * 8];
                bf16x8 bb1 = *(const bf16x8*)&Bs1[n][g * 8];
#pragma unroll
                for (int mi = 0; mi < 4; ++mi) {
                    acc[mi][ni] = __builtin_amdgcn_mfma_f32_16x16x32_bf16(a0[mi], bb0, acc[mi][ni], 0, 0, 0);
                    acc[mi][ni] = __builtin_amdgcn_mfma_f32_16x16x32_bf16(a0[mi], bb1, acc[mi][ni], 0, 0, 0);
                    acc[mi][ni] = __builtin_amdgcn_mfma_f32_16x16x32_bf16(a1[mi], bb0, acc[mi][ni], 0, 0, 0);
                }
            }
        }
    }
    // epilogue
#pragma unroll
    for (int ni = 0; ni < 4; ++ni) {
        int j = j0 + wcol * 64 + ni * 16 + cc;
        float cj = cvec[j];
#pragma unroll
        for (int mi = 0; mi < 4; ++mi) {
#pragma unroll
            for (int i = 0; i < 4; ++i) {
                int b = b0 + wrow * 64 + mi * 16 + g * 4 + i;
                float z = acc[mi][ni][i] + cj;
                float m = 1.0f / (1.0f + __expf(-z));
                float nv = noise[(size_t)b * NHID + j];
                hout[(size_t)b * NHID + j] = (nv < m) ? (unsigned char)1 : (unsigned char)0;
                if (fabsf(nv - m) < 2.5e-4f) {
                    unsigned p = atomicAdd(hcnt, 1u);
                    if (p < HCAP) hflag[p] = ((unsigned)b << 12) | (unsigned)j;
                }
            }
        }
    }
}

// ---------------- k5: exact f64 recheck of flagged h bits ----------------
__global__ __launch_bounds__(256) void k5_recheck_h(
    const float* __restrict__ vd, const float* __restrict__ cd, const float* __restrict__ noise,
    const float* __restrict__ W, const float* __restrict__ Bm, const float* __restrict__ cvec,
    const unsigned* __restrict__ hcnt, const unsigned* __restrict__ hflag,
    unsigned char* __restrict__ h) {
    const int gw = (blockIdx.x * 256 + threadIdx.x) >> 6, lane = threadIdx.x & 63;
    const int nw = gridDim.x * 4;
    unsigned n = *hcnt; if (n > HCAP) n = HCAP;
    for (unsigned e = gw; e < n; e += nw) {
        unsigned p = hflag[e];
        int b = p >> 12, j = p & 4095;
        double s = 0.0;
        for (int k = lane; k < NVIS; k += 64)
            s += (double)vd[(size_t)b * NVIS + k] * (double)W[(size_t)k * NHID + j];
        for (int k = lane; k < NCOND; k += 64)
            s += (double)cd[(size_t)b * NCOND + k] * (double)Bm[(size_t)k * NHID + j];
        for (int m = 32; m; m >>= 1) s += __shfl_xor(s, m);
        if (lane == 0) {
            double z = s + (double)cvec[j];
            double mm = 1.0 / (1.0 + exp(-z));
            h[(size_t)b * NHID + j] = ((double)noise[(size_t)b * NHID + j] < mm) ? 1 : 0;
        }
    }
}

// ---------------- k2: pre = h@W^T + u@A + b ; per-(row,block) top2 ----------------
template <bool PRESPLIT>
__global__ __launch_bounds__(256) void k2_gemm(
    const unsigned char* __restrict__ hin, const float* __restrict__ cd, const float* __restrict__ W,
    const unsigned short* __restrict__ u0p, const unsigned short* __restrict__ u1p,
    const unsigned short* __restrict__ W0p, const unsigned short* __restrict__ W1p,
    const unsigned short* __restrict__ AT0, const unsigned short* __restrict__ AT1,
    const float* __restrict__ bvec, float4* __restrict__ blockbest) {
    __shared__ __align__(16) unsigned short As0[128][32], As1[128][32], Bs0[128][32], Bs1[128][32];
    __shared__ float4 mbuf[2][128];
    const int t = threadIdx.x, lane = t & 63, wid = t >> 6;
    const int g = lane >> 4, cc = lane & 15;
    const int wrow = wid >> 1, wcol = wid & 1;
    const int b0 = blockIdx.y * 128, i0 = blockIdx.x * 128;
    f32x4 acc[4][4] = {};

    // phase 1: K = NHID, A = h (exact, 1 plane), B = W rows (2 planes): 2 products
    for (int k0 = 0; k0 < NHID; k0 += 32) {
        __syncthreads();
        stage_hbits(hin, b0, k0, As0, t);
        if (PRESPLIT) { stage_copy(W0p, i0, k0, NHID, Bs0, t); stage_copy(W1p, i0, k0, NHID, Bs1, t); }
        else          { stage_split(W, i0, k0, NHID, Bs0, Bs1, t); }
        __syncthreads();
        bf16x8 a[4];
#pragma unroll
        for (int mi = 0; mi < 4; ++mi) {
            int r = wrow * 64 + mi * 16 + cc;
            a[mi] = *(const bf16x8*)&As0[r][g * 8];
        }
#pragma unroll
        for (int ni = 0; ni < 4; ++ni) {
            int n = wcol * 64 + ni * 16 + cc;
            bf16x8 bb0 = *(const bf16x8*)&Bs0[n][g * 8];
            bf16x8 bb1 = *(const bf16x8*)&Bs1[n][g * 8];
#pragma unroll
            for (int mi = 0; mi < 4; ++mi) {
                acc[mi][ni] = __builtin_amdgcn_mfma_f32_16x16x32_bf16(a[mi], bb0, acc[mi][ni], 0, 0, 0);
                acc[mi][ni] = __builtin_amdgcn_mfma_f32_16x16x32_bf16(a[mi], bb1, acc[mi][ni], 0, 0, 0);
            }
        }
    }
    // phase 2: K = NCOND, A = u (split), B = AT planes: 3 products
    for (int k0 = 0; k0 < NCOND; k0 += 32) {
        __syncthreads();
        if (PRESPLIT) { stage_copy(u0p, b0, k0, NCOND, As0, t); stage_copy(u1p, b0, k0, NCOND, As1, t); }
        else          { stage_split(cd, b0, k0, NCOND, As0, As1, t); }
        stage_copy(AT0, i0, k0, NCOND, Bs0, t);
        stage_copy(AT1, i0, k0, NCOND, Bs1, t);
        __syncthreads();
        bf16x8 a0[4], a1[4];
#pragma unroll
        for (int mi = 0; mi < 4; ++mi) {
            int r = wrow * 64 + mi * 16 + cc;
            a0[mi] = *(const bf16x8*)&As0[r][g * 8];
            a1[mi] = *(const bf16x8*)&As1[r][g * 8];
        }
#pragma unroll
        for (int ni = 0; ni < 4; ++ni) {
            int n = wcol * 64 + ni * 16 + cc;
            bf16x8 bb0 = *(const bf16x8*)&Bs0[n][g * 8];
            bf16x8 bb1 = *(const bf16x8*)&Bs1[n][g * 8];
#pragma unroll
            for (int mi = 0; mi < 4; ++mi) {
                acc[mi][ni] = __builtin_amdgcn_mfma_f32_16x16x32_bf16(a0[mi], bb0, acc[mi][ni], 0, 0, 0);
                acc[mi][ni] = __builtin_amdgcn_mfma_f32_16x16x32_bf16(a0[mi], bb1, acc[mi][ni], 0, 0, 0);
                acc[mi][ni] = __builtin_amdgcn_mfma_f32_16x16x32_bf16(a1[mi], bb0, acc[mi][ni], 0, 0, 0);
            }
        }
    }
    // epilogue: + bias, per-row top2 across this block's 128 cols
#pragma unroll
    for (int ni = 0; ni < 4; ++ni) {
        int col = i0 + wcol * 64 + ni * 16 + cc;
        float bb = bvec[col];
#pragma unroll
        for (int mi = 0; mi < 4; ++mi)
#pragma unroll
            for (int i = 0; i < 4; ++i) acc[mi][ni][i] += bb;
    }
#pragma unroll
    for (int mi = 0; mi < 4; ++mi) {
#pragma unroll
        for (int i = 0; i < 4; ++i) {
            float best = acc[mi][0][i];
            unsigned bidx = (unsigned)(i0 + wcol * 64 + cc);
            float sec = -3.4e38f;
#pragma unroll
            for (int ni = 1; ni < 4; ++ni)
                merge3(best, bidx, sec, acc[mi][ni][i],
                       (unsigned)(i0 + wcol * 64 + ni * 16 + cc), -3.4e38f);
#pragma unroll
            for (int m = 1; m < 16; m <<= 1) {
                float ob = __shfl_xor(best, m);
                unsigned oi = __shfl_xor(bidx, m);
                float os = __shfl_xor(sec, m);
                merge3(best, bidx, sec, ob, oi, os);
            }
            if (cc == 0)
                mbuf[wcol][wrow * 64 + mi * 16 + g * 4 + i] =
                    make_float4(best, sec, __uint_as_float(bidx), 0.f);
        }
    }
    __syncthreads();
    if (t < 128) {
        float4 f0 = mbuf[0][t], f1 = mbuf[1][t];
        float best = f0.x, sec = f0.y;
        unsigned bidx = __float_as_uint(f0.z);
        merge3(best, bidx, sec, f1.x, __float_as_uint(f1.z), f1.y);
        blockbest[(size_t)(b0 + t) * 8 + blockIdx.x] = make_float4(best, sec, __uint_as_float(bidx), 0.f);
    }
}

// ---------------- k3: merge 8 block-top2 per row; flag near-ties ----------------
__global__ __launch_bounds__(256) void k3_merge(
    const float4* __restrict__ blockbest, unsigned* __restrict__ rowbest,
    unsigned* __restrict__ rcnt, unsigned* __restrict__ rowflag) {
    const int t = threadIdx.x;
    const int row = blockIdx.x * 32 + (t >> 3), e = t & 7;
    float4 f = blockbest[(size_t)row * 8 + e];
    float best = f.x, sec = f.y;
    unsigned idx = __float_as_uint(f.z);
#pragma unroll
    for (int m = 1; m < 8; m <<= 1) {
        float ob = __shfl_xor(best, m);
        unsigned oi = __shfl_xor(idx, m);
        float os = __shfl_xor(sec, m);
        merge3(best, idx, sec, ob, oi, os);
    }
    if (e == 0) {
        rowbest[row] = idx;
        if (best - sec < 8e-3f) {
            unsigned p = atomicAdd(rcnt, 1u);
            rowflag[p] = (unsigned)row;   // p < 4096 by construction
        }
    }
}

// ---------------- onehot write (all rows, fast-path argmax) ----------------
__global__ __launch_bounds__(256) void k_onehot(const unsigned* __restrict__ rowbest,
                                                float* __restrict__ out) {
    const int row = blockIdx.x;
    const unsigned idx = rowbest[row];
    const int base = threadIdx.x * 4;
    float4 o;
    o.x = (base + 0 == (int)idx) ? 1.f : 0.f;
    o.y = (base + 1 == (int)idx) ? 1.f : 0.f;
    o.z = (base + 2 == (int)idx) ? 1.f : 0.f;
    o.w = (base + 3 == (int)idx) ? 1.f : 0.f;
    *(float4*)(out + (size_t)row * NVIS + base) = o;
}

// ---------------- k6a: exact f64 pre for flagged rows ----------------
__global__ __launch_bounds__(256) void k6_rows_pre(
    const unsigned char* __restrict__ h, const float* __restrict__ cd,
    const float* __restrict__ W, const float* __restrict__ A, const float* __restrict__ bvec,
    const unsigned* __restrict__ rcnt, const unsigned* __restrict__ rowflag,
    double* __restrict__ prebuf) {
    const int gw = (blockIdx.x * 256 + threadIdx.x) >> 6, lane = threadIdx.x & 63;
    const int nw = gridDim.x * 4;
    unsigned n = *rcnt; if (n > RCAP) n = RCAP;
    for (unsigned e = gw; e < n * 1024u; e += nw) {
        int ri = e >> 10, i = e & 1023;
        int b = (int)rowflag[ri];
        double s = 0.0;
        for (int k = lane; k < NHID; k += 64)
            s += (double)h[(size_t)b * NHID + k] * (double)W[(size_t)i * NHID + k];
        for (int k = lane; k < NCOND; k += 64)
            s += (double)cd[(size_t)b * NCOND + k] * (double)A[(size_t)k * NVIS + i];
        for (int m = 32; m; m >>= 1) s += __shfl_xor(s, m);
        if (lane == 0) prebuf[(size_t)ri * 1024 + i] = s + (double)bvec[i];
    }
}

// ---------------- k6b: exact argmax + rewrite flagged rows ----------------
__global__ __launch_bounds__(256) void k6_rows_argmax(
    const unsigned* __restrict__ rcnt, const unsigned* __restrict__ rowflag,
    const double* __restrict__ prebuf, float* __restrict__ out) {
    __shared__ double sv[256];
    __shared__ int si[256];
    unsigned n = *rcnt; if (n > RCAP) n = RCAP;
    const int t = threadIdx.x;
    for (unsigned ri = blockIdx.x; ri < n; ri += gridDim.x) {
        const int row = (int)rowflag[ri];
        const double* pr = prebuf + (size_t)ri * 1024;
        double best = pr[t * 4];
        int bi = t * 4;
#pragma unroll
        for (int e = 1; e < 4; ++e) {
            double v = pr[t * 4 + e];
            if (v > best) { best = v; bi = t * 4 + e; }
        }
        sv[t] = best; si[t] = bi;
        __syncthreads();
        for (int s = 128; s; s >>= 1) {
            if (t < s) {
                double v2 = sv[t + s]; int i2 = si[t + s];
                if (v2 > sv[t] || (v2 == sv[t] && i2 < si[t])) { sv[t] = v2; si[t] = i2; }
            }
            __syncthreads();
        }
        const int amax = si[0];
        const int base = t * 4;
        float4 o;
        o.x = (base + 0 == amax) ? 1.f : 0.f;
        o.y = (base + 1 == amax) ? 1.f : 0.f;
        o.z = (base + 2 == amax) ? 1.f : 0.f;
        o.w = (base + 3 == amax) ? 1.f : 0.f;
        *(float4*)(out + (size_t)row * NVIS + base) = o;
        __syncthreads();
    }
}

// ---------------- launch ----------------
extern "C" void kernel_launch(void* const* d_in, const int* in_sizes, int n_in,
                              void* d_out, int out_size, void* d_ws, size_t ws_size,
                              hipStream_t stream) {
    const float* vd = (const float*)d_in[0];  // [4096,1024]
    const float* cd = (const float*)d_in[1];  // [4096,512]
    const float* nz = (const float*)d_in[2];  // [4096,4096]
    const float* W  = (const float*)d_in[3];  // [1024,4096]
    const float* bv = (const float*)d_in[4];  // [1024]
    const float* cv = (const float*)d_in[5];  // [4096]
    const float* Am = (const float*)d_in[6];  // [512,1024]
    const float* Bm = (const float*)d_in[7];  // [512,4096]
    float* out = (float*)d_out;
    char* w = (char*)d_ws;

    unsigned short* WT0  = (unsigned short*)(w + OFF_WT0);
    unsigned short* WT1  = (unsigned short*)(w + OFF_WT1);
    unsigned short* BmT0 = (unsigned short*)(w + OFF_BMT0);
    unsigned short* BmT1 = (unsigned short*)(w + OFF_BMT1);
    unsigned short* AT0  = (unsigned short*)(w + OFF_AT0);
    unsigned short* AT1  = (unsigned short*)(w + OFF_AT1);
    unsigned char*  hbuf = (unsigned char*)(w + OFF_H);
    float4*   blockbest  = (float4*)(w + OFF_BB);
    unsigned* hflag      = (unsigned*)(w + OFF_HFLAG);
    unsigned* rowflag    = (unsigned*)(w + OFF_RFLAG);
    unsigned* rowbest    = (unsigned*)(w + OFF_RBEST);
    unsigned* counters   = (unsigned*)(w + OFF_CNT);
    double*   prebuf     = (double*)(w + OFF_PREB);
    unsigned* hcnt = &counters[0];
    unsigned* rcnt = &counters[1];

    const bool big = (ws_size >= WS_BIG);
    unsigned short *v0p = nullptr, *v1p = nullptr, *u0p = nullptr, *u1p = nullptr,
                   *W0p = nullptr, *W1p = nullptr;
    if (big) {
        v0p = (unsigned short*)(w + OFF_V0); v1p = (unsigned short*)(w + OFF_V1);
        u0p = (unsigned short*)(w + OFF_U0); u1p = (unsigned short*)(w + OFF_U1);
        W0p = (unsigned short*)(w + OFF_W0); W1p = (unsigned short*)(w + OFF_W1);
    }

    kz_zero<<<1, 64, 0, stream>>>(counters);
    transpose_split<<<dim3(NHID / 32, NVIS / 32), 256, 0, stream>>>(W, NVIS, NHID, WT0, WT1);
    transpose_split<<<dim3(NHID / 32, NCOND / 32), 256, 0, stream>>>(Bm, NCOND, NHID, BmT0, BmT1);
    transpose_split<<<dim3(NVIS / 32, NCOND / 32), 256, 0, stream>>>(Am, NCOND, NVIS, AT0, AT1);
    if (big) {
        split_planes<<<2048, 256, 0, stream>>>(vd, BATCH * NVIS / 4, v0p, v1p);
        split_planes<<<2048, 256, 0, stream>>>(cd, BATCH * NCOND / 4, u0p, u1p);
        split_planes<<<2048, 256, 0, stream>>>(W, NVIS * NHID / 4, W0p, W1p);
        k1_gemm<true><<<dim3(NHID / 128, BATCH / 128), 256, 0, stream>>>(
            vd, cd, nz, v0p, v1p, u0p, u1p, WT0, WT1, BmT0, BmT1, cv, hbuf, hcnt, hflag);
    } else {
        k1_gemm<false><<<dim3(NHID / 128, BATCH / 128), 256, 0, stream>>>(
            vd, cd, nz, v0p, v1p, u0p, u1p, WT0, WT1, BmT0, BmT1, cv, hbuf, hcnt, hflag);
    }
    k5_recheck_h<<<256, 256, 0, stream>>>(vd, cd, nz, W, Bm, cv, hcnt, hflag, hbuf);
    if (big) {
        k2_gemm<true><<<dim3(NVIS / 128, BATCH / 128), 256, 0, stream>>>(
            hbuf, cd, W, u0p, u1p, W0p, W1p, AT0, AT1, bv, blockbest);
    } else {
        k2_gemm<false><<<dim3(NVIS / 128, BATCH / 128), 256, 0, stream>>>(
            hbuf, cd, W, u0p, u1p, W0p, W1p, AT0, AT1, bv, blockbest);
    }
    k3_merge<<<BATCH / 32, 256, 0, stream>>>(blockbest, rowbest, rcnt, rowflag);
    k_onehot<<<BATCH, 256, 0, stream>>>(rowbest, out);
    k6_rows_pre<<<512, 256, 0, stream>>>(hbuf, cd, W, Am, bv, rcnt, rowflag, prebuf);
    k6_rows_argmax<<<64, 256, 0, stream>>>(rcnt, rowflag, prebuf, out);
}

// Round 3
// 698.312 us; speedup vs baseline: 3.1461x; 1.1174x over previous
//
#include <hip/hip_runtime.h>
#include <math.h>

static constexpr int BATCH = 4096;
static constexpr int NVIS  = 1024;
static constexpr int NHID  = 4096;
static constexpr int NCOND = 512;

typedef __attribute__((ext_vector_type(8))) short bf16x8;
typedef __attribute__((ext_vector_type(4))) float f32x4;

static constexpr unsigned HCAP = 131072;
static constexpr unsigned RCAP = 256;
static constexpr size_t MB = 1u << 20;

// ---------------- small-mode ws layout (proven, 45.03 MiB) ----------------
static constexpr size_t OFF_WT0   = 0;                      // [4096][1024] bf16
static constexpr size_t OFF_WT1   = OFF_WT0 + 8388608;
static constexpr size_t OFF_BMT0  = OFF_WT1 + 8388608;      // [4096][512] bf16
static constexpr size_t OFF_BMT1  = OFF_BMT0 + 4194304;
static constexpr size_t OFF_AT0   = OFF_BMT1 + 4194304;     // [1024][512] bf16
static constexpr size_t OFF_AT1   = OFF_AT0 + 1048576;
static constexpr size_t OFF_H     = OFF_AT1 + 1048576;      // [4096][4096] u8
static constexpr size_t OFF_BB    = OFF_H + 16777216;       // blockbest [4096][8] float4
static constexpr size_t OFF_HFLAG = OFF_BB + 524288;
static constexpr size_t OFF_RFLAG = OFF_HFLAG + 524288;
static constexpr size_t OFF_RBEST = OFF_RFLAG + 16384;
static constexpr size_t OFF_CNT   = OFF_RBEST + 16384;
static constexpr size_t OFF_PREB  = OFF_CNT + 256;          // [256][1024] f64
static constexpr size_t WS_SMALL  = OFF_PREB + 2097152;

// ---------------- full-mode ws layout (~101.6 MiB) ----------------
static constexpr size_t F_WT0   = 0;                 // W^T planes [4096][1024]
static constexpr size_t F_WT1   = F_WT0  + 8*MB;
static constexpr size_t F_BMT0  = F_WT1  + 8*MB;     // B^T planes [4096][512]
static constexpr size_t F_BMT1  = F_BMT0 + 4*MB;
static constexpr size_t F_AT0   = F_BMT1 + 4*MB;     // A^T planes [1024][512]
static constexpr size_t F_AT1   = F_AT0  + 1*MB;
static constexpr size_t F_V0    = F_AT1  + 1*MB;     // vd planes [4096][1024]
static constexpr size_t F_V1    = F_V0   + 8*MB;
static constexpr size_t F_U0    = F_V1   + 8*MB;     // cd planes [4096][512]
static constexpr size_t F_U1    = F_U0   + 4*MB;
static constexpr size_t F_WR0   = F_U1   + 4*MB;     // W row-major planes [1024][4096]
static constexpr size_t F_WR1   = F_WR0  + 8*MB;
static constexpr size_t F_H     = F_WR1  + 8*MB;     // h bf16 [4096][4096]
static constexpr size_t F_BB    = F_H    + 32*MB;    // blockbest [4096][16] float4
static constexpr size_t F_HFLAG = F_BB   + 1*MB;
static constexpr size_t F_RFLAG = F_HFLAG + 512*1024;
static constexpr size_t F_RBEST = F_RFLAG + 16384;
static constexpr size_t F_CNT   = F_RBEST + 16384;
static constexpr size_t F_PREB  = F_CNT  + 256;
static constexpr size_t WS_FULL = F_PREB + 2*MB;

// ---------------- helpers ----------------
__device__ __forceinline__ void gload16(const void* g, void* l) {
    __builtin_amdgcn_global_load_lds(
        (const __attribute__((address_space(1))) void*)g,
        (__attribute__((address_space(3))) void*)l, 16, 0, 0);
}

__device__ __forceinline__ void split1(float x, unsigned short& hi, unsigned short& lo) {
    unsigned u = __float_as_uint(x);
    unsigned r = u + 0x7FFFu + ((u >> 16) & 1u);      // RN-even f32->bf16
    hi = (unsigned short)(r >> 16);
    float rem = x - __uint_as_float(r & 0xFFFF0000u); // exact (Sterbenz)
    unsigned u2 = __float_as_uint(rem);
    unsigned r2 = u2 + 0x7FFFu + ((u2 >> 16) & 1u);
    lo = (unsigned short)(r2 >> 16);
}

// top2 merge with first-index tiebreak; invariant s<=b on both inputs
__device__ __forceinline__ void merge3(float& b, unsigned& ix, float& s,
                                       float b2, unsigned i2, float s2) {
    if (b2 > b || (b2 == b && i2 < ix)) { s = fmaxf(b, s2); b = b2; ix = i2; }
    else                                { s = fmaxf(s, b2); }
}

// ---------------- prep kernels ----------------
__global__ void kz_zero(unsigned* c) { if (threadIdx.x < 64) c[threadIdx.x] = 0; }

// src [R][C] f32 -> d0/d1 [C][R] bf16 hi/lo planes
__global__ __launch_bounds__(256) void transpose_split(
    const float* __restrict__ src, int R, int C,
    unsigned short* __restrict__ d0, unsigned short* __restrict__ d1) {
    __shared__ float tile[32][33];
    const int c0 = blockIdx.x * 32, r0 = blockIdx.y * 32;
    const int tx = threadIdx.x & 31, ty = threadIdx.x >> 5;
#pragma unroll
    for (int e = 0; e < 4; ++e)
        tile[ty + e * 8][tx] = src[(size_t)(r0 + ty + e * 8) * C + c0 + tx];
    __syncthreads();
#pragma unroll
    for (int e = 0; e < 4; ++e) {
        int c = c0 + ty + e * 8;
        unsigned short hi, lo;
        split1(tile[tx][ty + e * 8], hi, lo);
        d0[(size_t)c * R + r0 + tx] = hi;
        d1[(size_t)c * R + r0 + tx] = lo;
    }
}

// elementwise split: src f32[n4*4] -> p0/p1 bf16 planes (same layout)
__global__ __launch_bounds__(256) void split_planes(
    const float* __restrict__ src, int n4,
    unsigned short* __restrict__ p0, unsigned short* __restrict__ p1) {
    for (int i = blockIdx.x * 256 + threadIdx.x; i < n4; i += gridDim.x * 256) {
        float4 v = ((const float4*)src)[i];
        unsigned short h0,h1,h2,h3,l0,l1,l2,l3;
        split1(v.x,h0,l0); split1(v.y,h1,l1); split1(v.z,h2,l2); split1(v.w,h3,l3);
        ((ushort4*)p0)[i] = make_ushort4(h0,h1,h2,h3);
        ((ushort4*)p1)[i] = make_ushort4(l0,l1,l2,l3);
    }
}

// ---------------- small-mode staging helpers ----------------
__device__ __forceinline__ void stage_copy(const unsigned short* __restrict__ p,
                                           int r0, int k0, int stride,
                                           unsigned short (*lds)[32], int t) {
#pragma unroll
    for (int e = 0; e < 2; ++e) {
        int idx = t + e * 256, row = idx >> 2, s = idx & 3;
        *(bf16x8*)&lds[row][s * 8] =
            *(const bf16x8*)(p + (size_t)(r0 + row) * stride + k0 + s * 8);
    }
}
__device__ __forceinline__ void stage_split(const float* __restrict__ p,
                                            int r0, int k0, int stride,
                                            unsigned short (*l0)[32], unsigned short (*l1)[32], int t) {
#pragma unroll
    for (int e = 0; e < 4; ++e) {
        int idx = t + e * 256, row = idx >> 3, q = idx & 7;
        const float4 v = *(const float4*)(p + (size_t)(r0 + row) * stride + k0 + q * 4);
        unsigned short h0,h1,h2,h3, s0,s1,s2,s3;
        split1(v.x,h0,s0); split1(v.y,h1,s1); split1(v.z,h2,s2); split1(v.w,h3,s3);
        *(ushort4*)&l0[row][q * 4] = make_ushort4(h0,h1,h2,h3);
        *(ushort4*)&l1[row][q * 4] = make_ushort4(s0,s1,s2,s3);
    }
}
__device__ __forceinline__ void stage_hbits(const unsigned char* __restrict__ h,
                                            int r0, int k0,
                                            unsigned short (*lds)[32], int t) {
#pragma unroll
    for (int e = 0; e < 4; ++e) {
        int idx = t + e * 256, row = idx >> 3, q = idx & 7;
        uchar4 u = *(const uchar4*)(h + (size_t)(r0 + row) * NHID + k0 + q * 4);
        *(ushort4*)&lds[row][q * 4] = make_ushort4(u.x ? 0x3F80 : 0, u.y ? 0x3F80 : 0,
                                                   u.z ? 0x3F80 : 0, u.w ? 0x3F80 : 0);
    }
}

// ===========================================================================
// FULL-mode k1: z = v@W + u@B + c ; h(bf16) = noise < sigmoid(z); flag boundary
// All staging via global_load_lds (linear LDS dest) with chunk-XOR pre-swizzled
// global source (involution: chunk s holds global chunk s^(row&3)).
// grid (NHID/128, BATCH/128) x 256
// ===========================================================================
__global__ __launch_bounds__(256) void k1_full(
    const float* __restrict__ noise,
    const unsigned short* __restrict__ v0p, const unsigned short* __restrict__ v1p,
    const unsigned short* __restrict__ u0p, const unsigned short* __restrict__ u1p,
    const unsigned short* __restrict__ WT0, const unsigned short* __restrict__ WT1,
    const unsigned short* __restrict__ BmT0, const unsigned short* __restrict__ BmT1,
    const float* __restrict__ cvec, unsigned short* __restrict__ hout,
    unsigned* __restrict__ hcnt, unsigned* __restrict__ hflag) {
    __shared__ __align__(16) unsigned short As0[128][32], As1[128][32], Bs0[128][32], Bs1[128][32];
    const int t = threadIdx.x, lane = t & 63, wid = t >> 6;
    const int g = lane >> 4, cc = lane & 15;
    const int wrow = wid >> 1, wcol = wid & 1;
    const int b0 = blockIdx.y * 128, j0 = blockIdx.x * 128;
    f32x4 acc[4][4] = {};

    for (int ph = 0; ph < 2; ++ph) {
        const int K = ph ? NCOND : NVIS;
        const unsigned short* A0 = ph ? u0p : v0p;
        const unsigned short* A1 = ph ? u1p : v1p;
        const unsigned short* B0 = ph ? BmT0 : WT0;
        const unsigned short* B1 = ph ? BmT1 : WT1;
        for (int k0 = 0; k0 < K; k0 += 32) {
            __syncthreads();
#pragma unroll
            for (int e = 0; e < 2; ++e) {
                int idx = t + e * 256, row = idx >> 2, s = idx & 3;
                int sc = s ^ (row & 3);                       // swizzled source chunk
                size_t ldd = (size_t)idx * 8;                 // linear LDS dest (ushorts)
                gload16(A0 + (size_t)(b0 + row) * K + k0 + sc * 8, (unsigned short*)As0 + ldd);
                gload16(A1 + (size_t)(b0 + row) * K + k0 + sc * 8, (unsigned short*)As1 + ldd);
                gload16(B0 + (size_t)(j0 + row) * K + k0 + sc * 8, (unsigned short*)Bs0 + ldd);
                gload16(B1 + (size_t)(j0 + row) * K + k0 + sc * 8, (unsigned short*)Bs1 + ldd);
            }
            __syncthreads();
            const int col = (g ^ (cc & 3)) * 8;               // swizzled read chunk
            bf16x8 a0[4], a1[4];
#pragma unroll
            for (int mi = 0; mi < 4; ++mi) {
                int r = wrow * 64 + mi * 16 + cc;
                a0[mi] = *(const bf16x8*)&As0[r][col];
                a1[mi] = *(const bf16x8*)&As1[r][col];
            }
#pragma unroll
            for (int ni = 0; ni < 4; ++ni) {
                int n = wcol * 64 + ni * 16 + cc;
                bf16x8 bb0 = *(const bf16x8*)&Bs0[n][col];
                bf16x8 bb1 = *(const bf16x8*)&Bs1[n][col];
#pragma unroll
                for (int mi = 0; mi < 4; ++mi) {
                    acc[mi][ni] = __builtin_amdgcn_mfma_f32_16x16x32_bf16(a0[mi], bb0, acc[mi][ni], 0, 0, 0);
                    acc[mi][ni] = __builtin_amdgcn_mfma_f32_16x16x32_bf16(a0[mi], bb1, acc[mi][ni], 0, 0, 0);
                    acc[mi][ni] = __builtin_amdgcn_mfma_f32_16x16x32_bf16(a1[mi], bb0, acc[mi][ni], 0, 0, 0);
                }
            }
        }
    }
#pragma unroll
    for (int ni = 0; ni < 4; ++ni) {
        int j = j0 + wcol * 64 + ni * 16 + cc;
        float cj = cvec[j];
#pragma unroll
        for (int mi = 0; mi < 4; ++mi) {
#pragma unroll
            for (int i = 0; i < 4; ++i) {
                int b = b0 + wrow * 64 + mi * 16 + g * 4 + i;
                float z = acc[mi][ni][i] + cj;
                float m = 1.0f / (1.0f + __expf(-z));
                float nv = noise[(size_t)b * NHID + j];
                hout[(size_t)b * NHID + j] = (nv < m) ? (unsigned short)0x3F80 : (unsigned short)0;
                if (fabsf(nv - m) < 2.5e-4f) {
                    unsigned p = atomicAdd(hcnt, 1u);
                    if (p < HCAP) hflag[p] = ((unsigned)b << 12) | (unsigned)j;
                }
            }
        }
    }
}

// ===========================================================================
// FULL-mode k2: pre = h@W^T + u@A + b ; per-(row,64col-block) top2
// tile 128(M)x64(N), grid (NVIS/64, BATCH/128) = 512 blocks (2/CU)
// ===========================================================================
__global__ __launch_bounds__(256) void k2_full(
    const unsigned short* __restrict__ hbf,
    const unsigned short* __restrict__ u0p, const unsigned short* __restrict__ u1p,
    const unsigned short* __restrict__ W0p, const unsigned short* __restrict__ W1p,
    const unsigned short* __restrict__ AT0, const unsigned short* __restrict__ AT1,
    const float* __restrict__ bvec, float4* __restrict__ blockbest) {
    __shared__ __align__(16) unsigned short As0[128][32], As1[128][32], Bs0[64][32], Bs1[64][32];
    __shared__ float4 mbuf[2][128];
    const int t = threadIdx.x, lane = t & 63, wid = t >> 6;
    const int g = lane >> 4, cc = lane & 15;
    const int wrow = wid >> 1, wcol = wid & 1;
    const int b0 = blockIdx.y * 128, i0 = blockIdx.x * 64;
    f32x4 acc[4][2] = {};

    // phase 1: K = NHID; A = h (exact bf16, 1 plane), B = W rows (2 planes)
    for (int k0 = 0; k0 < NHID; k0 += 32) {
        __syncthreads();
#pragma unroll
        for (int e = 0; e < 2; ++e) {
            int idx = t + e * 256, row = idx >> 2, s = idx & 3;
            int sc = s ^ (row & 3);
            gload16(hbf + (size_t)(b0 + row) * NHID + k0 + sc * 8, (unsigned short*)As0 + (size_t)idx * 8);
        }
        {
            int row = t >> 2, s = t & 3, sc = s ^ (row & 3);
            size_t go = (size_t)(i0 + row) * NHID + k0 + sc * 8;
            gload16(W0p + go, (unsigned short*)Bs0 + (size_t)t * 8);
            gload16(W1p + go, (unsigned short*)Bs1 + (size_t)t * 8);
        }
        __syncthreads();
        const int col = (g ^ (cc & 3)) * 8;
        bf16x8 a[4];
#pragma unroll
        for (int mi = 0; mi < 4; ++mi)
            a[mi] = *(const bf16x8*)&As0[wrow * 64 + mi * 16 + cc][col];
#pragma unroll
        for (int ni = 0; ni < 2; ++ni) {
            int n = wcol * 32 + ni * 16 + cc;
            bf16x8 bb0 = *(const bf16x8*)&Bs0[n][col];
            bf16x8 bb1 = *(const bf16x8*)&Bs1[n][col];
#pragma unroll
            for (int mi = 0; mi < 4; ++mi) {
                acc[mi][ni] = __builtin_amdgcn_mfma_f32_16x16x32_bf16(a[mi], bb0, acc[mi][ni], 0, 0, 0);
                acc[mi][ni] = __builtin_amdgcn_mfma_f32_16x16x32_bf16(a[mi], bb1, acc[mi][ni], 0, 0, 0);
            }
        }
    }
    // phase 2: K = NCOND; A = u planes, B = A^T planes
    for (int k0 = 0; k0 < NCOND; k0 += 32) {
        __syncthreads();
#pragma unroll
        for (int e = 0; e < 2; ++e) {
            int idx = t + e * 256, row = idx >> 2, s = idx & 3;
            int sc = s ^ (row & 3);
            size_t go = (size_t)(b0 + row) * NCOND + k0 + sc * 8;
            size_t ldd = (size_t)idx * 8;
            gload16(u0p + go, (unsigned short*)As0 + ldd);
            gload16(u1p + go, (unsigned short*)As1 + ldd);
        }
        {
            int row = t >> 2, s = t & 3, sc = s ^ (row & 3);
            size_t go = (size_t)(i0 + row) * NCOND + k0 + sc * 8;
            gload16(AT0 + go, (unsigned short*)Bs0 + (size_t)t * 8);
            gload16(AT1 + go, (unsigned short*)Bs1 + (size_t)t * 8);
        }
        __syncthreads();
        const int col = (g ^ (cc & 3)) * 8;
        bf16x8 a0[4], a1[4];
#pragma unroll
        for (int mi = 0; mi < 4; ++mi) {
            int r = wrow * 64 + mi * 16 + cc;
            a0[mi] = *(const bf16x8*)&As0[r][col];
            a1[mi] = *(const bf16x8*)&As1[r][col];
        }
#pragma unroll
        for (int ni = 0; ni < 2; ++ni) {
            int n = wcol * 32 + ni * 16 + cc;
            bf16x8 bb0 = *(const bf16x8*)&Bs0[n][col];
            bf16x8 bb1 = *(const bf16x8*)&Bs1[n][col];
#pragma unroll
            for (int mi = 0; mi < 4; ++mi) {
                acc[mi][ni] = __builtin_amdgcn_mfma_f32_16x16x32_bf16(a0[mi], bb0, acc[mi][ni], 0, 0, 0);
                acc[mi][ni] = __builtin_amdgcn_mfma_f32_16x16x32_bf16(a0[mi], bb1, acc[mi][ni], 0, 0, 0);
                acc[mi][ni] = __builtin_amdgcn_mfma_f32_16x16x32_bf16(a1[mi], bb0, acc[mi][ni], 0, 0, 0);
            }
        }
    }
    // epilogue: + bias, per-row top2 across this block's 64 cols
#pragma unroll
    for (int ni = 0; ni < 2; ++ni) {
        int colb = i0 + wcol * 32 + ni * 16 + cc;
        float bb = bvec[colb];
#pragma unroll
        for (int mi = 0; mi < 4; ++mi)
#pragma unroll
            for (int i = 0; i < 4; ++i) acc[mi][ni][i] += bb;
    }
#pragma unroll
    for (int mi = 0; mi < 4; ++mi) {
#pragma unroll
        for (int i = 0; i < 4; ++i) {
            float best = acc[mi][0][i];
            unsigned bidx = (unsigned)(i0 + wcol * 32 + cc);
            float sec = -3.4e38f;
            merge3(best, bidx, sec, acc[mi][1][i],
                   (unsigned)(i0 + wcol * 32 + 16 + cc), -3.4e38f);
#pragma unroll
            for (int m = 1; m < 16; m <<= 1) {
                float ob = __shfl_xor(best, m);
                unsigned oi = __shfl_xor(bidx, m);
                float os = __shfl_xor(sec, m);
                merge3(best, bidx, sec, ob, oi, os);
            }
            if (cc == 0)
                mbuf[wcol][wrow * 64 + mi * 16 + g * 4 + i] =
                    make_float4(best, sec, __uint_as_float(bidx), 0.f);
        }
    }
    __syncthreads();
    if (t < 128) {
        float4 f0 = mbuf[0][t], f1 = mbuf[1][t];
        float best = f0.x, sec = f0.y;
        unsigned bidx = __float_as_uint(f0.z);
        merge3(best, bidx, sec, f1.x, __float_as_uint(f1.z), f1.y);
        blockbest[(size_t)(b0 + t) * 16 + blockIdx.x] = make_float4(best, sec, __uint_as_float(bidx), 0.f);
    }
}

// ===========================================================================
// SMALL-mode k1/k2 (round-2 proven path, reg-staged, no swizzle)
// ===========================================================================
__global__ __launch_bounds__(256) void k1_small(
    const float* __restrict__ vd, const float* __restrict__ cd, const float* __restrict__ noise,
    const unsigned short* __restrict__ WT0, const unsigned short* __restrict__ WT1,
    const unsigned short* __restrict__ BmT0, const unsigned short* __restrict__ BmT1,
    const float* __restrict__ cvec, unsigned char* __restrict__ hout,
    unsigned* __restrict__ hcnt, unsigned* __restrict__ hflag) {
    __shared__ __align__(16) unsigned short As0[128][32], As1[128][32], Bs0[128][32], Bs1[128][32];
    const int t = threadIdx.x, lane = t & 63, wid = t >> 6;
    const int g = lane >> 4, cc = lane & 15;
    const int wrow = wid >> 1, wcol = wid & 1;
    const int b0 = blockIdx.y * 128, j0 = blockIdx.x * 128;
    f32x4 acc[4][4] = {};

    for (int ph = 0; ph < 2; ++ph) {
        const int K = ph ? NCOND : NVIS;
        for (int k0 = 0; k0 < K; k0 += 32) {
            __syncthreads();
            if (ph == 0) {
                stage_split(vd, b0, k0, NVIS, As0, As1, t);
                stage_copy(WT0, j0, k0, NVIS, Bs0, t);
                stage_copy(WT1, j0, k0, NVIS, Bs1, t);
            } else {
                stage_split(cd, b0, k0, NCOND, As0, As1, t);
                stage_copy(BmT0, j0, k0, NCOND, Bs0, t);
                stage_copy(BmT1, j0, k0, NCOND, Bs1, t);
            }
            __syncthreads();
            bf16x8 a0[4], a1[4];
#pragma unroll
            for (int mi = 0; mi < 4; ++mi) {
                int r = wrow * 64 + mi * 16 + cc;
                a0[mi] = *(const bf16x8*)&As0[r][g * 8];
                a1[mi] = *(const bf16x8*)&As1[r][g * 8];
            }
#pragma unroll
            for (int ni = 0; ni < 4; ++ni) {
                int n = wcol * 64 + ni * 16 + cc;
                bf16x8 bb0 = *(const bf16x8*)&Bs0[n][g * 8];
                bf16x8 bb1 = *(const bf16x8*)&Bs1[n][g * 8];
#pragma unroll
                for (int mi = 0; mi < 4; ++mi) {
                    acc[mi][ni] = __builtin_amdgcn_mfma_f32_16x16x32_bf16(a0[mi], bb0, acc[mi][ni], 0, 0, 0);
                    acc[mi][ni] = __builtin_amdgcn_mfma_f32_16x16x32_bf16(a0[mi], bb1, acc[mi][ni], 0, 0, 0);
                    acc[mi][ni] = __builtin_amdgcn_mfma_f32_16x16x32_bf16(a1[mi], bb0, acc[mi][ni], 0, 0, 0);
                }
            }
        }
    }
#pragma unroll
    for (int ni = 0; ni < 4; ++ni) {
        int j = j0 + wcol * 64 + ni * 16 + cc;
        float cj = cvec[j];
#pragma unroll
        for (int mi = 0; mi < 4; ++mi) {
#pragma unroll
            for (int i = 0; i < 4; ++i) {
                int b = b0 + wrow * 64 + mi * 16 + g * 4 + i;
                float z = acc[mi][ni][i] + cj;
                float m = 1.0f / (1.0f + __expf(-z));
                float nv = noise[(size_t)b * NHID + j];
                hout[(size_t)b * NHID + j] = (nv < m) ? (unsigned char)1 : (unsigned char)0;
                if (fabsf(nv - m) < 2.5e-4f) {
                    unsigned p = atomicAdd(hcnt, 1u);
                    if (p < HCAP) hflag[p] = ((unsigned)b << 12) | (unsigned)j;
                }
            }
        }
    }
}

__global__ __launch_bounds__(256) void k2_small(
    const unsigned char* __restrict__ hin, const float* __restrict__ cd, const float* __restrict__ W,
    const unsigned short* __restrict__ AT0, const unsigned short* __restrict__ AT1,
    const float* __restrict__ bvec, float4* __restrict__ blockbest) {
    __shared__ __align__(16) unsigned short As0[128][32], As1[128][32], Bs0[128][32], Bs1[128][32];
    __shared__ float4 mbuf[2][128];
    const int t = threadIdx.x, lane = t & 63, wid = t >> 6;
    const int g = lane >> 4, cc = lane & 15;
    const int wrow = wid >> 1, wcol = wid & 1;
    const int b0 = blockIdx.y * 128, i0 = blockIdx.x * 128;
    f32x4 acc[4][4] = {};

    for (int k0 = 0; k0 < NHID; k0 += 32) {
        __syncthreads();
        stage_hbits(hin, b0, k0, As0, t);
        stage_split(W, i0, k0, NHID, Bs0, Bs1, t);
        __syncthreads();
        bf16x8 a[4];
#pragma unroll
        for (int mi = 0; mi < 4; ++mi)
            a[mi] = *(const bf16x8*)&As0[wrow * 64 + mi * 16 + cc][g * 8];
#pragma unroll
        for (int ni = 0; ni < 4; ++ni) {
            int n = wcol * 64 + ni * 16 + cc;
            bf16x8 bb0 = *(const bf16x8*)&Bs0[n][g * 8];
            bf16x8 bb1 = *(const bf16x8*)&Bs1[n][g * 8];
#pragma unroll
            for (int mi = 0; mi < 4; ++mi) {
                acc[mi][ni] = __builtin_amdgcn_mfma_f32_16x16x32_bf16(a[mi], bb0, acc[mi][ni], 0, 0, 0);
                acc[mi][ni] = __builtin_amdgcn_mfma_f32_16x16x32_bf16(a[mi], bb1, acc[mi][ni], 0, 0, 0);
            }
        }
    }
    for (int k0 = 0; k0 < NCOND; k0 += 32) {
        __syncthreads();
        stage_split(cd, b0, k0, NCOND, As0, As1, t);
        stage_copy(AT0, i0, k0, NCOND, Bs0, t);
        stage_copy(AT1, i0, k0, NCOND, Bs1, t);
        __syncthreads();
        bf16x8 a0[4], a1[4];
#pragma unroll
        for (int mi = 0; mi < 4; ++mi) {
            int r = wrow * 64 + mi * 16 + cc;
            a0[mi] = *(const bf16x8*)&As0[r][g * 8];
            a1[mi] = *(const bf16x8*)&As1[r][g * 8];
        }
#pragma unroll
        for (int ni = 0; ni < 4; ++ni) {
            int n = wcol * 64 + ni * 16 + cc;
            bf16x8 bb0 = *(const bf16x8*)&Bs0[n][g * 8];
            bf16x8 bb1 = *(const bf16x8*)&Bs1[n][g * 8];
#pragma unroll
            for (int mi = 0; mi < 4; ++mi) {
                acc[mi][ni] = __builtin_amdgcn_mfma_f32_16x16x32_bf16(a0[mi], bb0, acc[mi][ni], 0, 0, 0);
                acc[mi][ni] = __builtin_amdgcn_mfma_f32_16x16x32_bf16(a0[mi], bb1, acc[mi][ni], 0, 0, 0);
                acc[mi][ni] = __builtin_amdgcn_mfma_f32_16x16x32_bf16(a1[mi], bb0, acc[mi][ni], 0, 0, 0);
            }
        }
    }
#pragma unroll
    for (int ni = 0; ni < 4; ++ni) {
        int colb = i0 + wcol * 64 + ni * 16 + cc;
        float bb = bvec[colb];
#pragma unroll
        for (int mi = 0; mi < 4; ++mi)
#pragma unroll
            for (int i = 0; i < 4; ++i) acc[mi][ni][i] += bb;
    }
#pragma unroll
    for (int mi = 0; mi < 4; ++mi) {
#pragma unroll
        for (int i = 0; i < 4; ++i) {
            float best = acc[mi][0][i];
            unsigned bidx = (unsigned)(i0 + wcol * 64 + cc);
            float sec = -3.4e38f;
#pragma unroll
            for (int ni = 1; ni < 4; ++ni)
                merge3(best, bidx, sec, acc[mi][ni][i],
                       (unsigned)(i0 + wcol * 64 + ni * 16 + cc), -3.4e38f);
#pragma unroll
            for (int m = 1; m < 16; m <<= 1) {
                float ob = __shfl_xor(best, m);
                unsigned oi = __shfl_xor(bidx, m);
                float os = __shfl_xor(sec, m);
                merge3(best, bidx, sec, ob, oi, os);
            }
            if (cc == 0)
                mbuf[wcol][wrow * 64 + mi * 16 + g * 4 + i] =
                    make_float4(best, sec, __uint_as_float(bidx), 0.f);
        }
    }
    __syncthreads();
    if (t < 128) {
        float4 f0 = mbuf[0][t], f1 = mbuf[1][t];
        float best = f0.x, sec = f0.y;
        unsigned bidx = __float_as_uint(f0.z);
        merge3(best, bidx, sec, f1.x, __float_as_uint(f1.z), f1.y);
        blockbest[(size_t)(b0 + t) * 8 + blockIdx.x] = make_float4(best, sec, __uint_as_float(bidx), 0.f);
    }
}

// ---------------- k5: exact f64 recheck of flagged h bits ----------------
template <bool B16>
__global__ __launch_bounds__(256) void k5_recheck_h(
    const float* __restrict__ vd, const float* __restrict__ cd, const float* __restrict__ noise,
    const float* __restrict__ W, const float* __restrict__ Bm, const float* __restrict__ cvec,
    const unsigned* __restrict__ hcnt, const unsigned* __restrict__ hflag,
    void* __restrict__ h) {
    const int gw = (blockIdx.x * 256 + threadIdx.x) >> 6, lane = threadIdx.x & 63;
    const int nw = gridDim.x * 4;
    unsigned n = *hcnt; if (n > HCAP) n = HCAP;
    for (unsigned e = gw; e < n; e += nw) {
        unsigned p = hflag[e];
        int b = p >> 12, j = p & 4095;
        double s = 0.0;
        for (int k = lane; k < NVIS; k += 64)
            s += (double)vd[(size_t)b * NVIS + k] * (double)W[(size_t)k * NHID + j];
        for (int k = lane; k < NCOND; k += 64)
            s += (double)cd[(size_t)b * NCOND + k] * (double)Bm[(size_t)k * NHID + j];
        for (int m = 32; m; m >>= 1) s += __shfl_xor(s, m);
        if (lane == 0) {
            double z = s + (double)cvec[j];
            double mm = 1.0 / (1.0 + exp(-z));
            bool bit = (double)noise[(size_t)b * NHID + j] < mm;
            if (B16) ((unsigned short*)h)[(size_t)b * NHID + j] = bit ? (unsigned short)0x3F80 : (unsigned short)0;
            else     ((unsigned char*)h)[(size_t)b * NHID + j] = bit ? 1 : 0;
        }
    }
}

// ---------------- k3 variants: merge block-top2 per row; flag near-ties ----------------
__global__ __launch_bounds__(256) void k3_merge8(
    const float4* __restrict__ blockbest, unsigned* __restrict__ rowbest,
    unsigned* __restrict__ rcnt, unsigned* __restrict__ rowflag) {
    const int t = threadIdx.x;
    const int row = blockIdx.x * 32 + (t >> 3), e = t & 7;
    float4 f = blockbest[(size_t)row * 8 + e];
    float best = f.x, sec = f.y;
    unsigned idx = __float_as_uint(f.z);
#pragma unroll
    for (int m = 1; m < 8; m <<= 1) {
        float ob = __shfl_xor(best, m);
        unsigned oi = __shfl_xor(idx, m);
        float os = __shfl_xor(sec, m);
        merge3(best, idx, sec, ob, oi, os);
    }
    if (e == 0) {
        rowbest[row] = idx;
        if (best - sec < 8e-3f) {
            unsigned p = atomicAdd(rcnt, 1u);
            if (p < 4096) rowflag[p] = (unsigned)row;
        }
    }
}

__global__ __launch_bounds__(256) void k3_merge16(
    const float4* __restrict__ blockbest, unsigned* __restrict__ rowbest,
    unsigned* __restrict__ rcnt, unsigned* __restrict__ rowflag) {
    const int t = threadIdx.x;
    const int row = blockIdx.x * 16 + (t >> 4), e = t & 15;
    float4 f = blockbest[(size_t)row * 16 + e];
    float best = f.x, sec = f.y;
    unsigned idx = __float_as_uint(f.z);
#pragma unroll
    for (int m = 1; m < 16; m <<= 1) {
        float ob = __shfl_xor(best, m);
        unsigned oi = __shfl_xor(idx, m);
        float os = __shfl_xor(sec, m);
        merge3(best, idx, sec, ob, oi, os);
    }
    if (e == 0) {
        rowbest[row] = idx;
        if (best - sec < 8e-3f) {
            unsigned p = atomicAdd(rcnt, 1u);
            if (p < 4096) rowflag[p] = (unsigned)row;
        }
    }
}

// ---------------- onehot write (all rows, fast-path argmax) ----------------
__global__ __launch_bounds__(256) void k_onehot(const unsigned* __restrict__ rowbest,
                                                float* __restrict__ out) {
    const int row = blockIdx.x;
    const unsigned idx = rowbest[row];
    const int base = threadIdx.x * 4;
    float4 o;
    o.x = (base + 0 == (int)idx) ? 1.f : 0.f;
    o.y = (base + 1 == (int)idx) ? 1.f : 0.f;
    o.z = (base + 2 == (int)idx) ? 1.f : 0.f;
    o.w = (base + 3 == (int)idx) ? 1.f : 0.f;
    *(float4*)(out + (size_t)row * NVIS + base) = o;
}

// ---------------- k6a: exact f64 pre for flagged rows ----------------
template <bool B16>
__global__ __launch_bounds__(256) void k6_rows_pre(
    const void* __restrict__ h, const float* __restrict__ cd,
    const float* __restrict__ W, const float* __restrict__ A, const float* __restrict__ bvec,
    const unsigned* __restrict__ rcnt, const unsigned* __restrict__ rowflag,
    double* __restrict__ prebuf) {
    const int gw = (blockIdx.x * 256 + threadIdx.x) >> 6, lane = threadIdx.x & 63;
    const int nw = gridDim.x * 4;
    unsigned n = *rcnt; if (n > RCAP) n = RCAP;
    for (unsigned e = gw; e < n * 1024u; e += nw) {
        int ri = e >> 10, i = e & 1023;
        int b = (int)rowflag[ri];
        double s = 0.0;
        for (int k = lane; k < NHID; k += 64) {
            double hv = B16 ? (((const unsigned short*)h)[(size_t)b * NHID + k] ? 1.0 : 0.0)
                            : (double)((const unsigned char*)h)[(size_t)b * NHID + k];
            s += hv * (double)W[(size_t)i * NHID + k];
        }
        for (int k = lane; k < NCOND; k += 64)
            s += (double)cd[(size_t)b * NCOND + k] * (double)A[(size_t)k * NVIS + i];
        for (int m = 32; m; m >>= 1) s += __shfl_xor(s, m);
        if (lane == 0) prebuf[(size_t)ri * 1024 + i] = s + (double)bvec[i];
    }
}

// ---------------- k6b: exact argmax + rewrite flagged rows ----------------
__global__ __launch_bounds__(256) void k6_rows_argmax(
    const unsigned* __restrict__ rcnt, const unsigned* __restrict__ rowflag,
    const double* __restrict__ prebuf, float* __restrict__ out) {
    __shared__ double sv[256];
    __shared__ int si[256];
    unsigned n = *rcnt; if (n > RCAP) n = RCAP;
    const int t = threadIdx.x;
    for (unsigned ri = blockIdx.x; ri < n; ri += gridDim.x) {
        const int row = (int)rowflag[ri];
        const double* pr = prebuf + (size_t)ri * 1024;
        double best = pr[t * 4];
        int bi = t * 4;
#pragma unroll
        for (int e = 1; e < 4; ++e) {
            double v = pr[t * 4 + e];
            if (v > best) { best = v; bi = t * 4 + e; }
        }
        sv[t] = best; si[t] = bi;
        __syncthreads();
        for (int s = 128; s; s >>= 1) {
            if (t < s) {
                double v2 = sv[t + s]; int i2 = si[t + s];
                if (v2 > sv[t] || (v2 == sv[t] && i2 < si[t])) { sv[t] = v2; si[t] = i2; }
            }
            __syncthreads();
        }
        const int amax = si[0];
        const int base = t * 4;
        float4 o;
        o.x = (base + 0 == amax) ? 1.f : 0.f;
        o.y = (base + 1 == amax) ? 1.f : 0.f;
        o.z = (base + 2 == amax) ? 1.f : 0.f;
        o.w = (base + 3 == amax) ? 1.f : 0.f;
        *(float4*)(out + (size_t)row * NVIS + base) = o;
        __syncthreads();
    }
}

// ---------------- launch ----------------
extern "C" void kernel_launch(void* const* d_in, const int* in_sizes, int n_in,
                              void* d_out, int out_size, void* d_ws, size_t ws_size,
                              hipStream_t stream) {
    const float* vd = (const float*)d_in[0];  // [4096,1024]
    const float* cd = (const float*)d_in[1];  // [4096,512]
    const float* nz = (const float*)d_in[2];  // [4096,4096]
    const float* W  = (const float*)d_in[3];  // [1024,4096]
    const float* bv = (const float*)d_in[4];  // [1024]
    const float* cv = (const float*)d_in[5];  // [4096]
    const float* Am = (const float*)d_in[6];  // [512,1024]
    const float* Bm = (const float*)d_in[7];  // [512,4096]
    float* out = (float*)d_out;
    char* w = (char*)d_ws;

    const bool full = (ws_size >= WS_FULL);
    dim3 blk(256);

    if (full) {
        unsigned short* WT0  = (unsigned short*)(w + F_WT0);
        unsigned short* WT1  = (unsigned short*)(w + F_WT1);
        unsigned short* BmT0 = (unsigned short*)(w + F_BMT0);
        unsigned short* BmT1 = (unsigned short*)(w + F_BMT1);
        unsigned short* AT0  = (unsigned short*)(w + F_AT0);
        unsigned short* AT1  = (unsigned short*)(w + F_AT1);
        unsigned short* V0   = (unsigned short*)(w + F_V0);
        unsigned short* V1   = (unsigned short*)(w + F_V1);
        unsigned short* U0   = (unsigned short*)(w + F_U0);
        unsigned short* U1   = (unsigned short*)(w + F_U1);
        unsigned short* WR0  = (unsigned short*)(w + F_WR0);
        unsigned short* WR1  = (unsigned short*)(w + F_WR1);
        unsigned short* hbf  = (unsigned short*)(w + F_H);
        float4*   blockbest  = (float4*)(w + F_BB);
        unsigned* hflag      = (unsigned*)(w + F_HFLAG);
        unsigned* rowflag    = (unsigned*)(w + F_RFLAG);
        unsigned* rowbest    = (unsigned*)(w + F_RBEST);
        unsigned* counters   = (unsigned*)(w + F_CNT);
        double*   prebuf     = (double*)(w + F_PREB);
        unsigned* hcnt = &counters[0];
        unsigned* rcnt = &counters[1];

        kz_zero<<<1, 64, 0, stream>>>(counters);
        transpose_split<<<dim3(NHID / 32, NVIS / 32), blk, 0, stream>>>(W, NVIS, NHID, WT0, WT1);
        transpose_split<<<dim3(NHID / 32, NCOND / 32), blk, 0, stream>>>(Bm, NCOND, NHID, BmT0, BmT1);
        transpose_split<<<dim3(NVIS / 32, NCOND / 32), blk, 0, stream>>>(Am, NCOND, NVIS, AT0, AT1);
        split_planes<<<2048, blk, 0, stream>>>(vd, BATCH * NVIS / 4, V0, V1);
        split_planes<<<2048, blk, 0, stream>>>(cd, BATCH * NCOND / 4, U0, U1);
        split_planes<<<2048, blk, 0, stream>>>(W, NVIS * NHID / 4, WR0, WR1);
        k1_full<<<dim3(NHID / 128, BATCH / 128), blk, 0, stream>>>(
            nz, V0, V1, U0, U1, WT0, WT1, BmT0, BmT1, cv, hbf, hcnt, hflag);
        k5_recheck_h<true><<<256, blk, 0, stream>>>(vd, cd, nz, W, Bm, cv, hcnt, hflag, hbf);
        k2_full<<<dim3(NVIS / 64, BATCH / 128), blk, 0, stream>>>(
            hbf, U0, U1, WR0, WR1, AT0, AT1, bv, blockbest);
        k3_merge16<<<BATCH / 16, blk, 0, stream>>>(blockbest, rowbest, rcnt, rowflag);
        k_onehot<<<BATCH, blk, 0, stream>>>(rowbest, out);
        k6_rows_pre<true><<<512, blk, 0, stream>>>(hbf, cd, W, Am, bv, rcnt, rowflag, prebuf);
        k6_rows_argmax<<<64, blk, 0, stream>>>(rcnt, rowflag, prebuf, out);
    } else {
        unsigned short* WT0  = (unsigned short*)(w + OFF_WT0);
        unsigned short* WT1  = (unsigned short*)(w + OFF_WT1);
        unsigned short* BmT0 = (unsigned short*)(w + OFF_BMT0);
        unsigned short* BmT1 = (unsigned short*)(w + OFF_BMT1);
        unsigned short* AT0  = (unsigned short*)(w + OFF_AT0);
        unsigned short* AT1  = (unsigned short*)(w + OFF_AT1);
        unsigned char*  hbuf = (unsigned char*)(w + OFF_H);
        float4*   blockbest  = (float4*)(w + OFF_BB);
        unsigned* hflag      = (unsigned*)(w + OFF_HFLAG);
        unsigned* rowflag    = (unsigned*)(w + OFF_RFLAG);
        unsigned* rowbest    = (unsigned*)(w + OFF_RBEST);
        unsigned* counters   = (unsigned*)(w + OFF_CNT);
        double*   prebuf     = (double*)(w + OFF_PREB);
        unsigned* hcnt = &counters[0];
        unsigned* rcnt = &counters[1];

        kz_zero<<<1, 64, 0, stream>>>(counters);
        transpose_split<<<dim3(NHID / 32, NVIS / 32), blk, 0, stream>>>(W, NVIS, NHID, WT0, WT1);
        transpose_split<<<dim3(NHID / 32, NCOND / 32), blk, 0, stream>>>(Bm, NCOND, NHID, BmT0, BmT1);
        transpose_split<<<dim3(NVIS / 32, NCOND / 32), blk, 0, stream>>>(Am, NCOND, NVIS, AT0, AT1);
        k1_small<<<dim3(NHID / 128, BATCH / 128), blk, 0, stream>>>(
            vd, cd, nz, WT0, WT1, BmT0, BmT1, cv, hbuf, hcnt, hflag);
        k5_recheck_h<false><<<256, blk, 0, stream>>>(vd, cd, nz, W, Bm, cv, hcnt, hflag, hbuf);
        k2_small<<<dim3(NVIS / 128, BATCH / 128), blk, 0, stream>>>(
            hbuf, cd, W, AT0, AT1, bv, blockbest);
        k3_merge8<<<BATCH / 32, blk, 0, stream>>>(blockbest, rowbest, rcnt, rowflag);
        k_onehot<<<BATCH, blk, 0, stream>>>(rowbest, out);
        k6_rows_pre<false><<<512, blk, 0, stream>>>(hbuf, cd, W, Am, bv, rcnt, rowflag, prebuf);
        k6_rows_argmax<<<64, blk, 0, stream>>>(rcnt, rowflag, prebuf, out);
    }
}